// Round 3
// baseline (708.778 us; speedup 1.0000x reference)
//
#include <hip/hip_runtime.h>
#include <hip/hip_bf16.h>

#define NN 10000
#define NE 160000

#define SK_NORM   0.039528470752104741f   // 1/sqrt(640)
#define UP_NORM   0.125f                  // 1/8
#define M1_NORM   0.35355339059327373f    // 1/sqrt(8)
#define INV3      0.5773502691896258f
#define LIN_NORM  0.0027621358640099516f  // 1/sqrt(128)/32

__device__ __forceinline__ float siluf(float x) { return x / (1.0f + __expf(-x)); }

__device__ __forceinline__ unsigned short f2bf_bits(float x) {
    union { __hip_bfloat16 h; unsigned short u; } cv;
    cv.h = __float2bfloat16(x);
    return cv.u;
}

// ---------------- K0a: detect edge_index dtype (int64 vs int32).
// int64 little-endian with values < 2^31 => every odd int32 slot is 0.
__global__ __launch_bounds__(256) void k_detect(const int* __restrict__ ei32, int* __restrict__ flag) {
    __shared__ int cnt;
    if (threadIdx.x == 0) cnt = 0;
    __syncthreads();
    int z = 0;
    for (int i = threadIdx.x; i < 1024; i += 256)
        if (ei32[2 * i + 1] == 0) z++;
    atomicAdd(&cnt, z);
    __syncthreads();
    if (threadIdx.x == 0) flag[0] = (cnt >= 512) ? 1 : 0;
}

// ---------------- K0b: extract sender/receiver as int32 regardless of source dtype
__global__ __launch_bounds__(256) void k_cvt(const int* __restrict__ ei32, const int* __restrict__ flag,
                                             int* __restrict__ snd, int* __restrict__ rcv) {
    int e = blockIdx.x * 256 + threadIdx.x;
    if (e >= NE) return;
    if (flag[0]) {
        const long long* e64 = (const long long*)ei32;
        snd[e] = (int)e64[e];
        rcv[e] = (int)e64[NE + e];
    } else {
        snd[e] = ei32[e];
        rcv[e] = ei32[NE + e];
    }
}

// ---------------- K1a: sc_s = einsum('nu,na,uav->nv', x0, attrs, W_sk_s) * SK_NORM
__global__ __launch_bounds__(256) void k_sc_s(
    const float* __restrict__ node_attrs, const float* __restrict__ node_feats,
    const float* __restrict__ W_sk_s, float* __restrict__ sc_s) {
    int n = blockIdx.x * 256 + threadIdx.x;
    int vg = blockIdx.y;              // 8 groups of 16 v's
    if (n >= NN) return;
    float attrs[10];
    #pragma unroll
    for (int a = 0; a < 10; a++) attrs[a] = node_attrs[n * 10 + a];
    float acc[16];
    #pragma unroll
    for (int j = 0; j < 16; j++) acc[j] = 0.f;
    const float* Wbase = W_sk_s + vg * 16;
    for (int u = 0; u < 64; u++) {
        float xu = node_feats[n * 256 + u];
        #pragma unroll
        for (int a = 0; a < 10; a++) {
            float xa = xu * attrs[a];
            const float* w = Wbase + (u * 10 + a) * 128;
            #pragma unroll
            for (int j = 0; j < 16; j++) acc[j] += xa * w[j];
        }
    }
    float4* o = (float4*)(sc_s + n * 128 + vg * 16);
    #pragma unroll
    for (int q = 0; q < 4; q++)
        o[q] = make_float4(acc[q*4]*SK_NORM, acc[q*4+1]*SK_NORM, acc[q*4+2]*SK_NORM, acc[q*4+3]*SK_NORM);
}

// ---------------- K1b: sc_v = einsum('nui,na,uav->nvi', x1, attrs, W_sk_v) * SK_NORM
__global__ __launch_bounds__(256) void k_sc_v(
    const float* __restrict__ node_attrs, const float* __restrict__ node_feats,
    const float* __restrict__ W_sk_v, float* __restrict__ sc_v) {
    int n = blockIdx.x * 256 + threadIdx.x;
    int vg = blockIdx.y;              // 8 groups of 8 v's
    if (n >= NN) return;
    float attrs[10];
    #pragma unroll
    for (int a = 0; a < 10; a++) attrs[a] = node_attrs[n * 10 + a];
    float acc[24];
    #pragma unroll
    for (int j = 0; j < 24; j++) acc[j] = 0.f;
    const float* Wbase = W_sk_v + vg * 8;
    for (int u = 0; u < 64; u++) {
        float x1i[3];
        #pragma unroll
        for (int i = 0; i < 3; i++) x1i[i] = node_feats[n * 256 + 64 + u * 3 + i];
        float ws8[8];
        #pragma unroll
        for (int j = 0; j < 8; j++) ws8[j] = 0.f;
        #pragma unroll
        for (int a = 0; a < 10; a++) {
            const float* w = Wbase + (u * 10 + a) * 64;
            float av = attrs[a];
            #pragma unroll
            for (int j = 0; j < 8; j++) ws8[j] += av * w[j];
        }
        #pragma unroll
        for (int j = 0; j < 8; j++) {
            #pragma unroll
            for (int i = 0; i < 3; i++) acc[j * 3 + i] += x1i[i] * ws8[j];
        }
    }
    float4* o = (float4*)(sc_v + n * 192 + vg * 24);
    #pragma unroll
    for (int q = 0; q < 6; q++)
        o[q] = make_float4(acc[q*4]*SK_NORM, acc[q*4+1]*SK_NORM, acc[q*4+2]*SK_NORM, acc[q*4+3]*SK_NORM);
}

// ---------------- K1c: x0u = x0 @ W_up0 /8 ; x1u[n][i][v] = sum_u x1[n][u][i]*W_up1[u][v] /8
__global__ __launch_bounds__(256) void k_up(
    const float* __restrict__ node_feats, const float* __restrict__ W_up0,
    const float* __restrict__ W_up1, float* __restrict__ x0u, float* __restrict__ x1u) {
    int n = blockIdx.x * 256 + threadIdx.x;
    int p = blockIdx.y;               // 0..7
    if (n >= NN) return;
    float acc[32];
    #pragma unroll
    for (int j = 0; j < 32; j++) acc[j] = 0.f;
    if (p < 2) {
        const float* W = W_up0 + p * 32;
        for (int u = 0; u < 64; u++) {
            float xu = node_feats[n * 256 + u];
            const float* w = W + u * 64;
            #pragma unroll
            for (int j = 0; j < 32; j++) acc[j] += xu * w[j];
        }
        float4* o = (float4*)(x0u + n * 64 + p * 32);
        #pragma unroll
        for (int q = 0; q < 8; q++)
            o[q] = make_float4(acc[q*4]*UP_NORM, acc[q*4+1]*UP_NORM, acc[q*4+2]*UP_NORM, acc[q*4+3]*UP_NORM);
    } else {
        int q = p - 2; int i = q >> 1; int half = q & 1;
        const float* W = W_up1 + half * 32;
        for (int u = 0; u < 64; u++) {
            float xv = node_feats[n * 256 + 64 + u * 3 + i];
            const float* w = W + u * 64;
            #pragma unroll
            for (int j = 0; j < 32; j++) acc[j] += xv * w[j];
        }
        float4* o = (float4*)(x1u + n * 192 + i * 64 + half * 32);
        #pragma unroll
        for (int qq = 0; qq < 8; qq++)
            o[qq] = make_float4(acc[qq*4]*UP_NORM, acc[qq*4+1]*UP_NORM, acc[qq*4+2]*UP_NORM, acc[qq*4+3]*UP_NORM);
    }
}

// ---------------- K2: edge MLP -> tw (bf16, E x 256)
// thread-per-edge, 64-thread blocks; hidden vector lives in an LDS column (own column
// only, no cross-thread sharing => no barriers). Weight addresses are wave-uniform.
template<int OUTS>
__device__ __forceinline__ void mlp_layer(const __hip_bfloat16* colIn, __hip_bfloat16* colOut,
                                          const float* __restrict__ W, float scale) {
    #pragma unroll 1
    for (int cb = 0; cb < OUTS / 8; cb++) {
        float acc[8];
        #pragma unroll
        for (int j = 0; j < 8; j++) acc[j] = 0.f;
        #pragma unroll 8
        for (int k = 0; k < 64; k++) {
            float hk = __bfloat162float(colIn[k * 64]);
            const float* w = W + k * OUTS + cb * 8;
            #pragma unroll
            for (int j = 0; j < 8; j++) acc[j] += hk * w[j];
        }
        #pragma unroll
        for (int j = 0; j < 8; j++) colOut[(cb * 8 + j) * 64] = __float2bfloat16(siluf(acc[j] * scale));
    }
}

__global__ __launch_bounds__(64) void k_edge_mlp(
    const float* __restrict__ edge_feats,
    const float* __restrict__ M1, const float* __restrict__ M2,
    const float* __restrict__ M3, const float* __restrict__ M4,
    __hip_bfloat16* __restrict__ tw) {
    __shared__ __hip_bfloat16 hA[64 * 64];
    __shared__ __hip_bfloat16 hB[64 * 64];
    int t = threadIdx.x;
    long e = (long)blockIdx.x * 64 + t;
    if (e >= NE) return;
    __hip_bfloat16* colA = hA + t;
    __hip_bfloat16* colB = hB + t;

    float ef[8];
    #pragma unroll
    for (int r = 0; r < 8; r++) ef[r] = edge_feats[e * 8 + r] * M1_NORM;

    // layer 1: 8 -> 64
    #pragma unroll 1
    for (int cb = 0; cb < 8; cb++) {
        float acc[8];
        #pragma unroll
        for (int j = 0; j < 8; j++) acc[j] = 0.f;
        #pragma unroll
        for (int r = 0; r < 8; r++) {
            const float* w = M1 + r * 64 + cb * 8;
            #pragma unroll
            for (int j = 0; j < 8; j++) acc[j] += ef[r] * w[j];
        }
        #pragma unroll
        for (int j = 0; j < 8; j++) colA[(cb * 8 + j) * 64] = __float2bfloat16(siluf(acc[j]));
    }
    mlp_layer<64>(colA, colB, M2, 0.125f);   // layer 2
    mlp_layer<64>(colB, colA, M3, 0.125f);   // layer 3

    // layer 4: 64 -> 256, no silu, store bf16
    #pragma unroll 1
    for (int cb = 0; cb < 32; cb++) {
        float acc[8];
        #pragma unroll
        for (int j = 0; j < 8; j++) acc[j] = 0.f;
        #pragma unroll 8
        for (int k = 0; k < 64; k++) {
            float hk = __bfloat162float(colA[k * 64]);
            const float* w = M4 + k * 256 + cb * 8;
            #pragma unroll
            for (int j = 0; j < 8; j++) acc[j] += hk * w[j];
        }
        union { unsigned short us[8]; uint4 v; } pk;
        #pragma unroll
        for (int j = 0; j < 8; j++) pk.us[j] = f2bf_bits(acc[j] * 0.125f);
        *((uint4*)(tw + e * 256 + cb * 8)) = pk.v;
    }
}

// ---------------- K3: CSR build by receiver
__global__ __launch_bounds__(256) void k_hist(const int* __restrict__ rcv, int* __restrict__ counts) {
    int e = blockIdx.x * 256 + threadIdx.x;
    if (e < NE) atomicAdd(&counts[rcv[e]], 1);
}

__global__ __launch_bounds__(1024) void k_scan(const int* __restrict__ counts, int* __restrict__ offsets) {
    __shared__ int partial[1024];
    int t = threadIdx.x;
    const int CHUNK = (NN + 1023) / 1024;   // 10
    int base = t * CHUNK;
    int s = 0;
    for (int i = 0; i < CHUNK; i++) if (base + i < NN) s += counts[base + i];
    partial[t] = s;
    __syncthreads();
    for (int d = 1; d < 1024; d *= 2) {
        int v = (t >= d) ? partial[t - d] : 0;
        __syncthreads();
        partial[t] += v;
        __syncthreads();
    }
    int excl = (t == 0) ? 0 : partial[t - 1];
    for (int i = 0; i < CHUNK; i++) {
        if (base + i < NN) { offsets[base + i] = excl; excl += counts[base + i]; }
    }
    if (t == 1023) offsets[NN] = partial[1023];
}

__global__ __launch_bounds__(256) void k_fill(const int* __restrict__ rcv, const int* __restrict__ offsets,
                                              int* __restrict__ cursor, int* __restrict__ edge_list) {
    int e = blockIdx.x * 256 + threadIdx.x;
    if (e < NE) {
        int r = rcv[e];
        int pos = atomicAdd(&cursor[r], 1);
        edge_list[offsets[r] + pos] = e;
    }
}

// ---------------- K4: per-node gather + conv_tp + segment sum + lin + gate + output (f32)
__global__ __launch_bounds__(256) void k_gather(
    const int* __restrict__ snd, const int* __restrict__ offsets, const int* __restrict__ edge_list,
    const float* __restrict__ x0u, const float* __restrict__ x1u,
    const __hip_bfloat16* __restrict__ tw,
    const float* __restrict__ ear, const float* __restrict__ eai,
    const float* __restrict__ sc_s, const float* __restrict__ sc_v,
    const float* __restrict__ W_lin_s, const float* __restrict__ W_lin_v,
    float* __restrict__ out) {
    __shared__ float msg[1024];   // [0..127] ms_r, [128..255] ms_i, [256..639] mv_r(u*3+i), [640..1023] mv_i
    __shared__ float sval[256];   // post-lin s: [0..127] real, [128..255] imag
    __shared__ float vval[384];   // post-lin v: [0..191] real (v*3+i), [192..383] imag
    int n = blockIdx.x;
    int t = threadIdx.x;
    int u = t & 127;
    int ri = t >> 7;
    int beg = offsets[n], end = offsets[n + 1];
    const float* ea = ri ? eai : ear;
    float a0 = 0.f, a1 = 0.f, a2 = 0.f, a3 = 0.f;
    for (int j = beg; j < end; j++) {
        int e = edge_list[j];
        int s = snd[e];                     // sender
        float y0  = ea[e * 4 + 0];
        float y1a = ea[e * 4 + 1];
        float y1b = ea[e * 4 + 2];
        float y1c = ea[e * 4 + 3];
        if (u < 64) {
            float xs0 = x0u[s * 64 + u];
            float wA = __bfloat162float(tw[(long)e * 256 + u]);
            float wB = __bfloat162float(tw[(long)e * 256 + 64 + u]);
            a0 += xs0 * y0 * wA;
            float xb = xs0 * wB;
            a1 += xb * y1a; a2 += xb * y1b; a3 += xb * y1c;
        } else {
            int uu = u - 64;
            float xa = x1u[s * 192 + 0 * 64 + uu];
            float xb = x1u[s * 192 + 1 * 64 + uu];
            float xc = x1u[s * 192 + 2 * 64 + uu];
            float wC = __bfloat162float(tw[(long)e * 256 + 128 + uu]);
            float wD = __bfloat162float(tw[(long)e * 256 + 192 + uu]);
            a0 += (xa * y1a + xb * y1b + xc * y1c) * INV3 * wD;
            float yc = y0 * wC;
            a1 += xa * yc; a2 += xb * yc; a3 += xc * yc;
        }
    }
    msg[ri * 128 + u] = a0;
    int vb = 256 + ri * 384 + u * 3;
    msg[vb + 0] = a1; msg[vb + 1] = a2; msg[vb + 2] = a3;
    __syncthreads();

    // lin s: 256 outputs (one per thread)
    {
        float acc = 0.f;
        const float* wcol = W_lin_s + u;
        #pragma unroll 8
        for (int k = 0; k < 128; k++) acc += msg[ri * 128 + k] * wcol[k * 128];
        acc *= LIN_NORM;
        if (ri == 0) acc += sc_s[n * 128 + u];
        sval[t] = acc;
    }
    // lin v: 384 outputs
    for (int o = t; o < 384; o += 256) {
        int rib = (o >= 192) ? 1 : 0;
        int rem = o - rib * 192;
        int v = rem / 3;
        int i = rem - v * 3;
        float acc = 0.f;
        const float* wcol = W_lin_v + v;
        int mb = 256 + rib * 384 + i;
        #pragma unroll 8
        for (int k = 0; k < 128; k++) acc += msg[mb + k * 3] * wcol[k * 64];
        acc *= LIN_NORM;
        if (!rib) acc += sc_v[n * 192 + rem];
        vval[o] = acc;
    }
    __syncthreads();

    // gate + interleaved f32 store: out[(n*256+c)*2 + {0,1}] = {real, imag}
    float re, im;
    if (t < 64) {
        re = siluf(sval[t]);
        im = siluf(sval[128 + t]);
    } else {
        int rem = t - 64;           // 0..191
        int v = rem / 3;
        re = vval[rem] * siluf(sval[64 + v]);
        im = vval[192 + rem] * siluf(sval[192 + v]);
    }
    ((float2*)out)[(long)n * 256 + t] = make_float2(re, im);
}

extern "C" void kernel_launch(void* const* d_in, const int* in_sizes, int n_in,
                              void* d_out, int out_size, void* d_ws, size_t ws_size,
                              hipStream_t stream) {
    const float* node_attrs = (const float*)d_in[0];
    const float* node_feats = (const float*)d_in[1];
    const float* ear        = (const float*)d_in[2];
    const float* eai        = (const float*)d_in[3];
    const float* edge_feats = (const float*)d_in[4];
    const float* W_up0      = (const float*)d_in[5];
    const float* W_up1      = (const float*)d_in[6];
    const float* M1         = (const float*)d_in[7];
    const float* M2         = (const float*)d_in[8];
    const float* M3         = (const float*)d_in[9];
    const float* M4         = (const float*)d_in[10];
    const float* W_lin_s    = (const float*)d_in[11];
    const float* W_lin_v    = (const float*)d_in[12];
    const float* W_sk_s     = (const float*)d_in[13];
    const float* W_sk_v     = (const float*)d_in[14];
    const int*   ei         = (const int*)d_in[15];

    char* ws = (char*)d_ws;
    size_t o_x0u = 0;
    size_t o_x1u = o_x0u + (size_t)NN * 64 * 4;
    size_t o_scs = o_x1u + (size_t)NN * 192 * 4;
    size_t o_scv = o_scs + (size_t)NN * 128 * 4;
    size_t o_tw  = o_scv + (size_t)NN * 192 * 4;
    size_t o_cnt = o_tw  + (size_t)NE * 256 * 2;
    size_t o_cur = o_cnt + (size_t)NN * 4;
    size_t o_ofs = o_cur + (size_t)NN * 4;
    size_t o_el  = o_ofs + (size_t)(NN + 1) * 4 + 60;   // pad to 16B
    size_t o_snd = o_el  + (size_t)NE * 4;
    size_t o_rcv = o_snd + (size_t)NE * 4;
    size_t o_flg = o_rcv + (size_t)NE * 4;
    float* x0u = (float*)(ws + o_x0u);
    float* x1u = (float*)(ws + o_x1u);
    float* sc_s = (float*)(ws + o_scs);
    float* sc_v = (float*)(ws + o_scv);
    __hip_bfloat16* tw = (__hip_bfloat16*)(ws + o_tw);
    int* counts  = (int*)(ws + o_cnt);
    int* cursor  = (int*)(ws + o_cur);
    int* offsets = (int*)(ws + o_ofs);
    int* elist   = (int*)(ws + o_el);
    int* snd     = (int*)(ws + o_snd);
    int* rcv     = (int*)(ws + o_rcv);
    int* flag    = (int*)(ws + o_flg);

    // zero counts + cursor (adjacent)
    hipMemsetAsync(ws + o_cnt, 0, (size_t)NN * 8, stream);

    dim3 b256(256), b64(64), b1024(1024);
    dim3 gNodes((NN + 255) / 256, 8);
    k_detect<<<dim3(1), b256, 0, stream>>>(ei, flag);
    k_cvt   <<<dim3((NE + 255) / 256), b256, 0, stream>>>(ei, flag, snd, rcv);
    k_sc_s<<<gNodes, b256, 0, stream>>>(node_attrs, node_feats, W_sk_s, sc_s);
    k_sc_v<<<gNodes, b256, 0, stream>>>(node_attrs, node_feats, W_sk_v, sc_v);
    k_up  <<<gNodes, b256, 0, stream>>>(node_feats, W_up0, W_up1, x0u, x1u);
    k_edge_mlp<<<dim3((NE + 63) / 64), b64, 0, stream>>>(edge_feats, M1, M2, M3, M4, tw);
    k_hist<<<dim3((NE + 255) / 256), b256, 0, stream>>>(rcv, counts);
    k_scan<<<dim3(1), b1024, 0, stream>>>(counts, offsets);
    k_fill<<<dim3((NE + 255) / 256), b256, 0, stream>>>(rcv, offsets, cursor, elist);
    k_gather<<<dim3(NN), b256, 0, stream>>>(snd, offsets, elist, x0u, x1u, tw, ear, eai,
                                            sc_s, sc_v, W_lin_s, W_lin_v,
                                            (float*)d_out);
}

// Round 4
// 480.478 us; speedup vs baseline: 1.4752x; 1.4752x over previous
//
#include <hip/hip_runtime.h>
#include <hip/hip_bf16.h>

#define NN 10000
#define NE 160000

#define SK_NORM   0.039528470752104741f   // 1/sqrt(640)
#define UP_NORM   0.125f                  // 1/8
#define M1_NORM   0.35355339059327373f    // 1/sqrt(8)
#define INV3      0.5773502691896258f
#define LIN_NORM  0.0027621358640099516f  // 1/sqrt(128)/32

__device__ __forceinline__ float siluf(float x) { return x / (1.0f + __expf(-x)); }

__device__ __forceinline__ unsigned short f2bf_bits(float x) {
    union { __hip_bfloat16 h; unsigned short u; } cv;
    cv.h = __float2bfloat16(x);
    return cv.u;
}

typedef short bf16x8 __attribute__((ext_vector_type(8)));
typedef float f32x4  __attribute__((ext_vector_type(4)));

// ---------------- K0a: detect edge_index dtype (int64 vs int32).
__global__ __launch_bounds__(256) void k_detect(const int* __restrict__ ei32, int* __restrict__ flag) {
    __shared__ int cnt;
    if (threadIdx.x == 0) cnt = 0;
    __syncthreads();
    int z = 0;
    for (int i = threadIdx.x; i < 1024; i += 256)
        if (ei32[2 * i + 1] == 0) z++;
    atomicAdd(&cnt, z);
    __syncthreads();
    if (threadIdx.x == 0) flag[0] = (cnt >= 512) ? 1 : 0;
}

// ---------------- K0b: extract sender/receiver as int32 regardless of source dtype
__global__ __launch_bounds__(256) void k_cvt(const int* __restrict__ ei32, const int* __restrict__ flag,
                                             int* __restrict__ snd, int* __restrict__ rcv) {
    int e = blockIdx.x * 256 + threadIdx.x;
    if (e >= NE) return;
    if (flag[0]) {
        const long long* e64 = (const long long*)ei32;
        snd[e] = (int)e64[e];
        rcv[e] = (int)e64[NE + e];
    } else {
        snd[e] = ei32[e];
        rcv[e] = ei32[NE + e];
    }
}

// ---------------- K1a: sc_s = einsum('nu,na,uav->nv', x0, attrs, W_sk_s) * SK_NORM
__global__ __launch_bounds__(256) void k_sc_s(
    const float* __restrict__ node_attrs, const float* __restrict__ node_feats,
    const float* __restrict__ W_sk_s, float* __restrict__ sc_s) {
    int n = blockIdx.x * 256 + threadIdx.x;
    int vg = blockIdx.y;              // 8 groups of 16 v's
    if (n >= NN) return;
    float attrs[10];
    #pragma unroll
    for (int a = 0; a < 10; a++) attrs[a] = node_attrs[n * 10 + a];
    float acc[16];
    #pragma unroll
    for (int j = 0; j < 16; j++) acc[j] = 0.f;
    const float* Wbase = W_sk_s + vg * 16;
    for (int u = 0; u < 64; u++) {
        float xu = node_feats[n * 256 + u];
        #pragma unroll
        for (int a = 0; a < 10; a++) {
            float xa = xu * attrs[a];
            const float* w = Wbase + (u * 10 + a) * 128;
            #pragma unroll
            for (int j = 0; j < 16; j++) acc[j] += xa * w[j];
        }
    }
    float4* o = (float4*)(sc_s + n * 128 + vg * 16);
    #pragma unroll
    for (int q = 0; q < 4; q++)
        o[q] = make_float4(acc[q*4]*SK_NORM, acc[q*4+1]*SK_NORM, acc[q*4+2]*SK_NORM, acc[q*4+3]*SK_NORM);
}

// ---------------- K1b: sc_v = einsum('nui,na,uav->nvi', x1, attrs, W_sk_v) * SK_NORM
__global__ __launch_bounds__(256) void k_sc_v(
    const float* __restrict__ node_attrs, const float* __restrict__ node_feats,
    const float* __restrict__ W_sk_v, float* __restrict__ sc_v) {
    int n = blockIdx.x * 256 + threadIdx.x;
    int vg = blockIdx.y;              // 8 groups of 8 v's
    if (n >= NN) return;
    float attrs[10];
    #pragma unroll
    for (int a = 0; a < 10; a++) attrs[a] = node_attrs[n * 10 + a];
    float acc[24];
    #pragma unroll
    for (int j = 0; j < 24; j++) acc[j] = 0.f;
    const float* Wbase = W_sk_v + vg * 8;
    for (int u = 0; u < 64; u++) {
        float x1i[3];
        #pragma unroll
        for (int i = 0; i < 3; i++) x1i[i] = node_feats[n * 256 + 64 + u * 3 + i];
        float ws8[8];
        #pragma unroll
        for (int j = 0; j < 8; j++) ws8[j] = 0.f;
        #pragma unroll
        for (int a = 0; a < 10; a++) {
            const float* w = Wbase + (u * 10 + a) * 64;
            float av = attrs[a];
            #pragma unroll
            for (int j = 0; j < 8; j++) ws8[j] += av * w[j];
        }
        #pragma unroll
        for (int j = 0; j < 8; j++) {
            #pragma unroll
            for (int i = 0; i < 3; i++) acc[j * 3 + i] += x1i[i] * ws8[j];
        }
    }
    float4* o = (float4*)(sc_v + n * 192 + vg * 24);
    #pragma unroll
    for (int q = 0; q < 6; q++)
        o[q] = make_float4(acc[q*4]*SK_NORM, acc[q*4+1]*SK_NORM, acc[q*4+2]*SK_NORM, acc[q*4+3]*SK_NORM);
}

// ---------------- K1c: x0u = x0 @ W_up0 /8 ; x1u[n][i][v] = sum_u x1[n][u][i]*W_up1[u][v] /8
__global__ __launch_bounds__(256) void k_up(
    const float* __restrict__ node_feats, const float* __restrict__ W_up0,
    const float* __restrict__ W_up1, float* __restrict__ x0u, float* __restrict__ x1u) {
    int n = blockIdx.x * 256 + threadIdx.x;
    int p = blockIdx.y;               // 0..7
    if (n >= NN) return;
    float acc[32];
    #pragma unroll
    for (int j = 0; j < 32; j++) acc[j] = 0.f;
    if (p < 2) {
        const float* W = W_up0 + p * 32;
        for (int u = 0; u < 64; u++) {
            float xu = node_feats[n * 256 + u];
            const float* w = W + u * 64;
            #pragma unroll
            for (int j = 0; j < 32; j++) acc[j] += xu * w[j];
        }
        float4* o = (float4*)(x0u + n * 64 + p * 32);
        #pragma unroll
        for (int q = 0; q < 8; q++)
            o[q] = make_float4(acc[q*4]*UP_NORM, acc[q*4+1]*UP_NORM, acc[q*4+2]*UP_NORM, acc[q*4+3]*UP_NORM);
    } else {
        int q = p - 2; int i = q >> 1; int half = q & 1;
        const float* W = W_up1 + half * 32;
        for (int u = 0; u < 64; u++) {
            float xv = node_feats[n * 256 + 64 + u * 3 + i];
            const float* w = W + u * 64;
            #pragma unroll
            for (int j = 0; j < 32; j++) acc[j] += xv * w[j];
        }
        float4* o = (float4*)(x1u + n * 192 + i * 64 + half * 32);
        #pragma unroll
        for (int qq = 0; qq < 8; qq++)
            o[qq] = make_float4(acc[qq*4]*UP_NORM, acc[qq*4+1]*UP_NORM, acc[qq*4+2]*UP_NORM, acc[qq*4+3]*UP_NORM);
    }
}

// ---------------- K2: edge MLP via MFMA -> tw (bf16, E x 256)
// 256 threads = 4 waves, 64 edges/block (16/wave). Weights bf16-transposed in LDS
// (Wt[n][k], padded rows, 16B-aligned). Hidden C->A repack through per-wave LDS tile.
// mfma_f32_16x16x32_bf16: A[m=lane&15][k=quad*8+j], B[k][n]: n=lane&15,k=quad*8+j,
// C: row(m)=quad*4+reg, col(n)=lane&15  [verified layouts, guide section 3]
#define W1_STRIDE 40    // K=32 (real 8, zero-padded) + 8 pad  -> 80 B rows (16B-aligned)
#define W_STRIDE  72    // K=64 + 8 pad                        -> 144 B rows (16B-aligned)
#define HID_STRIDE 72
#define OB_STRIDE  40   // 32 feats + 8 pad

__global__ __launch_bounds__(256) void k_edge_mlp(
    const float* __restrict__ edge_feats,
    const float* __restrict__ M1, const float* __restrict__ M2,
    const float* __restrict__ M3, const float* __restrict__ M4,
    __hip_bfloat16* __restrict__ tw) {
    __shared__ unsigned short w1t[64 * W1_STRIDE];
    __shared__ unsigned short w2t[64 * W_STRIDE];
    __shared__ unsigned short w3t[64 * W_STRIDE];
    __shared__ unsigned short w4t[256 * W_STRIDE];
    __shared__ unsigned short hid[4][16 * HID_STRIDE];
    __shared__ unsigned short obuf[4][16 * OB_STRIDE];

    int t = threadIdx.x;
    // ---- stage weights: transpose [K][N] -> Wt[n][k], bf16 ----
    for (int i = t; i < 64 * W1_STRIDE; i += 256) {
        int n = i / W1_STRIDE, k = i - n * W1_STRIDE;
        w1t[i] = (k < 8) ? f2bf_bits(M1[k * 64 + n]) : (unsigned short)0;
    }
    for (int i = t; i < 64 * 64; i += 256) {
        int k = i >> 6, n = i & 63;
        w2t[n * W_STRIDE + k] = f2bf_bits(M2[i]);
        w3t[n * W_STRIDE + k] = f2bf_bits(M3[i]);
    }
    for (int i = t; i < 64 * 256; i += 256) {
        int k = i >> 8, n = i & 255;
        w4t[n * W_STRIDE + k] = f2bf_bits(M4[i]);
    }
    __syncthreads();

    int wv = t >> 6;
    int lane = t & 63;
    int lo = lane & 15;
    int quad = lane >> 4;
    int ebase = blockIdx.x * 64 + wv * 16;
    unsigned short* myhid = hid[wv];
    unsigned short* myob  = obuf[wv];
    const f32x4 zacc = {0.f, 0.f, 0.f, 0.f};

    // ---- layer 1: [16x8] @ [8x64] (K padded to 32), silu ----
    bf16x8 a1 = {0, 0, 0, 0, 0, 0, 0, 0};
    if (quad == 0) {
        const float4* ef = (const float4*)(edge_feats + (long)(ebase + lo) * 8);
        float4 f0 = ef[0];
        float4 f1 = ef[1];
        union { unsigned short us[8]; bf16x8 v; } pk;
        pk.us[0] = f2bf_bits(f0.x * M1_NORM); pk.us[1] = f2bf_bits(f0.y * M1_NORM);
        pk.us[2] = f2bf_bits(f0.z * M1_NORM); pk.us[3] = f2bf_bits(f0.w * M1_NORM);
        pk.us[4] = f2bf_bits(f1.x * M1_NORM); pk.us[5] = f2bf_bits(f1.y * M1_NORM);
        pk.us[6] = f2bf_bits(f1.z * M1_NORM); pk.us[7] = f2bf_bits(f1.w * M1_NORM);
        a1 = pk.v;
    }
    {
        f32x4 acc[4];
        #pragma unroll
        for (int nt = 0; nt < 4; nt++) {
            bf16x8 b = *(const bf16x8*)&w1t[(nt * 16 + lo) * W1_STRIDE + quad * 8];
            acc[nt] = __builtin_amdgcn_mfma_f32_16x16x32_bf16(a1, b, zacc, 0, 0, 0);
        }
        #pragma unroll
        for (int nt = 0; nt < 4; nt++)
            #pragma unroll
            for (int r = 0; r < 4; r++)
                myhid[(quad * 4 + r) * HID_STRIDE + nt * 16 + lo] = f2bf_bits(siluf(acc[nt][r]));
    }

    // ---- layers 2,3: [16x64] @ [64x64] /8, silu ----
    const unsigned short* wts[2] = {w2t, w3t};
    #pragma unroll
    for (int L = 0; L < 2; L++) {
        const unsigned short* wt = wts[L];
        bf16x8 a0 = *(const bf16x8*)&myhid[lo * HID_STRIDE + quad * 8];
        bf16x8 a1v = *(const bf16x8*)&myhid[lo * HID_STRIDE + 32 + quad * 8];
        f32x4 acc[4];
        #pragma unroll
        for (int nt = 0; nt < 4; nt++) {
            bf16x8 b0 = *(const bf16x8*)&wt[(nt * 16 + lo) * W_STRIDE + quad * 8];
            bf16x8 b1 = *(const bf16x8*)&wt[(nt * 16 + lo) * W_STRIDE + 32 + quad * 8];
            acc[nt] = __builtin_amdgcn_mfma_f32_16x16x32_bf16(a0, b0, zacc, 0, 0, 0);
            acc[nt] = __builtin_amdgcn_mfma_f32_16x16x32_bf16(a1v, b1, acc[nt], 0, 0, 0);
        }
        #pragma unroll
        for (int nt = 0; nt < 4; nt++)
            #pragma unroll
            for (int r = 0; r < 4; r++)
                myhid[(quad * 4 + r) * HID_STRIDE + nt * 16 + lo] = f2bf_bits(siluf(acc[nt][r] * 0.125f));
    }

    // ---- layer 4: [16x64] @ [64x256] /8, store bf16 via 32-feat LDS rounds ----
    {
        bf16x8 a0 = *(const bf16x8*)&myhid[lo * HID_STRIDE + quad * 8];
        bf16x8 a1v = *(const bf16x8*)&myhid[lo * HID_STRIDE + 32 + quad * 8];
        int sedge = lane >> 2, sch = lane & 3;
        #pragma unroll 1
        for (int rd = 0; rd < 8; rd++) {
            f32x4 acc2[2];
            #pragma unroll
            for (int p = 0; p < 2; p++) {
                int n = (rd * 2 + p) * 16 + lo;
                bf16x8 b0 = *(const bf16x8*)&w4t[n * W_STRIDE + quad * 8];
                bf16x8 b1 = *(const bf16x8*)&w4t[n * W_STRIDE + 32 + quad * 8];
                acc2[p] = __builtin_amdgcn_mfma_f32_16x16x32_bf16(a0, b0, zacc, 0, 0, 0);
                acc2[p] = __builtin_amdgcn_mfma_f32_16x16x32_bf16(a1v, b1, acc2[p], 0, 0, 0);
            }
            #pragma unroll
            for (int p = 0; p < 2; p++)
                #pragma unroll
                for (int r = 0; r < 4; r++)
                    myob[(quad * 4 + r) * OB_STRIDE + p * 16 + lo] = f2bf_bits(acc2[p][r] * 0.125f);
            // wave-local LDS transpose read + coalesced 16B global store
            bf16x8 vv = *(const bf16x8*)&myob[sedge * OB_STRIDE + sch * 8];
            *(bf16x8*)(tw + (long)(ebase + sedge) * 256 + rd * 32 + sch * 8) = vv;
        }
    }
}

// ---------------- K3: CSR build by receiver
__global__ __launch_bounds__(256) void k_hist(const int* __restrict__ rcv, int* __restrict__ counts) {
    int e = blockIdx.x * 256 + threadIdx.x;
    if (e < NE) atomicAdd(&counts[rcv[e]], 1);
}

__global__ __launch_bounds__(1024) void k_scan(const int* __restrict__ counts, int* __restrict__ offsets) {
    __shared__ int partial[1024];
    int t = threadIdx.x;
    const int CHUNK = (NN + 1023) / 1024;   // 10
    int base = t * CHUNK;
    int s = 0;
    for (int i = 0; i < CHUNK; i++) if (base + i < NN) s += counts[base + i];
    partial[t] = s;
    __syncthreads();
    for (int d = 1; d < 1024; d *= 2) {
        int v = (t >= d) ? partial[t - d] : 0;
        __syncthreads();
        partial[t] += v;
        __syncthreads();
    }
    int excl = (t == 0) ? 0 : partial[t - 1];
    for (int i = 0; i < CHUNK; i++) {
        if (base + i < NN) { offsets[base + i] = excl; excl += counts[base + i]; }
    }
    if (t == 1023) offsets[NN] = partial[1023];
}

__global__ __launch_bounds__(256) void k_fill(const int* __restrict__ rcv, const int* __restrict__ offsets,
                                              int* __restrict__ cursor, int* __restrict__ edge_list) {
    int e = blockIdx.x * 256 + threadIdx.x;
    if (e < NE) {
        int r = rcv[e];
        int pos = atomicAdd(&cursor[r], 1);
        edge_list[offsets[r] + pos] = e;
    }
}

// ---------------- K4: per-node gather + conv_tp + segment sum + lin + gate + output (f32)
__global__ __launch_bounds__(256) void k_gather(
    const int* __restrict__ snd, const int* __restrict__ offsets, const int* __restrict__ edge_list,
    const float* __restrict__ x0u, const float* __restrict__ x1u,
    const __hip_bfloat16* __restrict__ tw,
    const float* __restrict__ ear, const float* __restrict__ eai,
    const float* __restrict__ sc_s, const float* __restrict__ sc_v,
    const float* __restrict__ W_lin_s, const float* __restrict__ W_lin_v,
    float* __restrict__ out) {
    __shared__ float msg[1024];   // [0..127] ms_r, [128..255] ms_i, [256..639] mv_r(u*3+i), [640..1023] mv_i
    __shared__ float sval[256];   // post-lin s: [0..127] real, [128..255] imag
    __shared__ float vval[384];   // post-lin v: [0..191] real (v*3+i), [192..383] imag
    int n = blockIdx.x;
    int t = threadIdx.x;
    int u = t & 127;
    int ri = t >> 7;
    int beg = offsets[n], end = offsets[n + 1];
    const float* ea = ri ? eai : ear;
    float a0 = 0.f, a1 = 0.f, a2 = 0.f, a3 = 0.f;
    for (int j = beg; j < end; j++) {
        int e = edge_list[j];
        int s = snd[e];                     // sender
        float y0  = ea[e * 4 + 0];
        float y1a = ea[e * 4 + 1];
        float y1b = ea[e * 4 + 2];
        float y1c = ea[e * 4 + 3];
        if (u < 64) {
            float xs0 = x0u[s * 64 + u];
            float wA = __bfloat162float(tw[(long)e * 256 + u]);
            float wB = __bfloat162float(tw[(long)e * 256 + 64 + u]);
            a0 += xs0 * y0 * wA;
            float xb = xs0 * wB;
            a1 += xb * y1a; a2 += xb * y1b; a3 += xb * y1c;
        } else {
            int uu = u - 64;
            float xa = x1u[s * 192 + 0 * 64 + uu];
            float xb = x1u[s * 192 + 1 * 64 + uu];
            float xc = x1u[s * 192 + 2 * 64 + uu];
            float wC = __bfloat162float(tw[(long)e * 256 + 128 + uu]);
            float wD = __bfloat162float(tw[(long)e * 256 + 192 + uu]);
            a0 += (xa * y1a + xb * y1b + xc * y1c) * INV3 * wD;
            float yc = y0 * wC;
            a1 += xa * yc; a2 += xb * yc; a3 += xc * yc;
        }
    }
    msg[ri * 128 + u] = a0;
    int vb = 256 + ri * 384 + u * 3;
    msg[vb + 0] = a1; msg[vb + 1] = a2; msg[vb + 2] = a3;
    __syncthreads();

    // lin s: 256 outputs (one per thread)
    {
        float acc = 0.f;
        const float* wcol = W_lin_s + u;
        #pragma unroll 8
        for (int k = 0; k < 128; k++) acc += msg[ri * 128 + k] * wcol[k * 128];
        acc *= LIN_NORM;
        if (ri == 0) acc += sc_s[n * 128 + u];
        sval[t] = acc;
    }
    // lin v: 384 outputs
    for (int o = t; o < 384; o += 256) {
        int rib = (o >= 192) ? 1 : 0;
        int rem = o - rib * 192;
        int v = rem / 3;
        int i = rem - v * 3;
        float acc = 0.f;
        const float* wcol = W_lin_v + v;
        int mb = 256 + rib * 384 + i;
        #pragma unroll 8
        for (int k = 0; k < 128; k++) acc += msg[mb + k * 3] * wcol[k * 64];
        acc *= LIN_NORM;
        if (!rib) acc += sc_v[n * 192 + rem];
        vval[o] = acc;
    }
    __syncthreads();

    // gate + interleaved f32 store: out[(n*256+c)*2 + {0,1}] = {real, imag}
    float re, im;
    if (t < 64) {
        re = siluf(sval[t]);
        im = siluf(sval[128 + t]);
    } else {
        int rem = t - 64;           // 0..191
        int v = rem / 3;
        re = vval[rem] * siluf(sval[64 + v]);
        im = vval[192 + rem] * siluf(sval[192 + v]);
    }
    ((float2*)out)[(long)n * 256 + t] = make_float2(re, im);
}

extern "C" void kernel_launch(void* const* d_in, const int* in_sizes, int n_in,
                              void* d_out, int out_size, void* d_ws, size_t ws_size,
                              hipStream_t stream) {
    const float* node_attrs = (const float*)d_in[0];
    const float* node_feats = (const float*)d_in[1];
    const float* ear        = (const float*)d_in[2];
    const float* eai        = (const float*)d_in[3];
    const float* edge_feats = (const float*)d_in[4];
    const float* W_up0      = (const float*)d_in[5];
    const float* W_up1      = (const float*)d_in[6];
    const float* M1         = (const float*)d_in[7];
    const float* M2         = (const float*)d_in[8];
    const float* M3         = (const float*)d_in[9];
    const float* M4         = (const float*)d_in[10];
    const float* W_lin_s    = (const float*)d_in[11];
    const float* W_lin_v    = (const float*)d_in[12];
    const float* W_sk_s     = (const float*)d_in[13];
    const float* W_sk_v     = (const float*)d_in[14];
    const int*   ei         = (const int*)d_in[15];

    char* ws = (char*)d_ws;
    size_t o_x0u = 0;
    size_t o_x1u = o_x0u + (size_t)NN * 64 * 4;
    size_t o_scs = o_x1u + (size_t)NN * 192 * 4;
    size_t o_scv = o_scs + (size_t)NN * 128 * 4;
    size_t o_tw  = o_scv + (size_t)NN * 192 * 4;
    size_t o_cnt = o_tw  + (size_t)NE * 256 * 2;
    size_t o_cur = o_cnt + (size_t)NN * 4;
    size_t o_ofs = o_cur + (size_t)NN * 4;
    size_t o_el  = o_ofs + (size_t)(NN + 1) * 4 + 60;   // pad to 16B
    size_t o_snd = o_el  + (size_t)NE * 4;
    size_t o_rcv = o_snd + (size_t)NE * 4;
    size_t o_flg = o_rcv + (size_t)NE * 4;
    float* x0u = (float*)(ws + o_x0u);
    float* x1u = (float*)(ws + o_x1u);
    float* sc_s = (float*)(ws + o_scs);
    float* sc_v = (float*)(ws + o_scv);
    __hip_bfloat16* tw = (__hip_bfloat16*)(ws + o_tw);
    int* counts  = (int*)(ws + o_cnt);
    int* cursor  = (int*)(ws + o_cur);
    int* offsets = (int*)(ws + o_ofs);
    int* elist   = (int*)(ws + o_el);
    int* snd     = (int*)(ws + o_snd);
    int* rcv     = (int*)(ws + o_rcv);
    int* flag    = (int*)(ws + o_flg);

    // zero counts + cursor (adjacent)
    hipMemsetAsync(ws + o_cnt, 0, (size_t)NN * 8, stream);

    dim3 b256(256), b1024(1024);
    dim3 gNodes((NN + 255) / 256, 8);
    k_detect<<<dim3(1), b256, 0, stream>>>(ei, flag);
    k_cvt   <<<dim3((NE + 255) / 256), b256, 0, stream>>>(ei, flag, snd, rcv);
    k_sc_s<<<gNodes, b256, 0, stream>>>(node_attrs, node_feats, W_sk_s, sc_s);
    k_sc_v<<<gNodes, b256, 0, stream>>>(node_attrs, node_feats, W_sk_v, sc_v);
    k_up  <<<gNodes, b256, 0, stream>>>(node_feats, W_up0, W_up1, x0u, x1u);
    k_edge_mlp<<<dim3(NE / 64), b256, 0, stream>>>(edge_feats, M1, M2, M3, M4, tw);
    k_hist<<<dim3((NE + 255) / 256), b256, 0, stream>>>(rcv, counts);
    k_scan<<<dim3(1), b1024, 0, stream>>>(counts, offsets);
    k_fill<<<dim3((NE + 255) / 256), b256, 0, stream>>>(rcv, offsets, cursor, elist);
    k_gather<<<dim3(NN), b256, 0, stream>>>(snd, offsets, elist, x0u, x1u, tw, ear, eai,
                                            sc_s, sc_v, W_lin_s, W_lin_v,
                                            (float*)d_out);
}